// Round 17
// baseline (467.786 us; speedup 1.0000x reference)
//
#include <hip/hip_runtime.h>

#define NB 8192
#define NT 1024
#define NH 10
#define ROWS_PER_WAVE 4     // 10 lanes/row, lanes 40..63 idle
#define ROWS_PER_BLOCK 16   // 4 waves/block

typedef float v2f __attribute__((ext_vector_type(2)));
typedef float v4f __attribute__((ext_vector_type(4)));

#define LOG2E 1.44269504088896340736f

__device__ __forceinline__ float rcpf(float x) { return __builtin_amdgcn_rcpf(x); }
__device__ __forceinline__ float exp2i(float x) {   // single v_exp_f32, no libm guards
    float r;
    asm("v_exp_f32 %0, %1" : "=v"(r) : "v"(x));
    return r;
}
// q accumulated in log2 domain with -log2e pre-scaled weights: sigm = 1/(1+2^q)
__device__ __forceinline__ float sigm2q(float q) { return rcpf(1.0f + exp2i(q)); }
// u accumulated with 2*log2e pre-scaled weights: tanh = 1 - 2/(2^u + 1)
__device__ __forceinline__ float tanh2u(float u) { return fmaf(-2.0f, rcpf(exp2i(u) + 1.0f), 1.0f); }

__device__ __forceinline__ v2f lo2(v4f a) { return __builtin_shufflevector(a, a, 0, 1); }
__device__ __forceinline__ v2f hi2(v4f a) { return __builtin_shufflevector(a, a, 2, 3); }
__device__ __forceinline__ v2f pkfma(v2f a, v2f b, v2f c) {  // -> v_pk_fma_f32 (no asm)
    return __builtin_elementwise_fma(a, b, c);
}

// Row of 10 weights as 5 v2f pairs (pk_fma operands).
struct W5 { v2f p[5]; };
__device__ __forceinline__ W5 loadrow_scaled(const float* __restrict__ q, float s) {
    W5 w;
#pragma unroll
    for (int k = 0; k < 5; ++k) w.p[k] = (v2f){q[2 * k] * s, q[2 * k + 1] * s};
    return w;
}
// bias + w . h   (5 pk_fma + 1 hsum)
__device__ __forceinline__ float dotW(const W5& w, v4f ha, v4f hb, v2f hc, float bias) {
    v2f acc = (v2f){bias, 0.0f};
    acc = pkfma(w.p[0], lo2(ha), acc);
    acc = pkfma(w.p[1], hi2(ha), acc);
    acc = pkfma(w.p[2], lo2(hb), acc);
    acc = pkfma(w.p[3], hi2(hb), acc);
    acc = pkfma(w.p[4], hc, acc);
    return acc.x + acc.y;
}
// bias + wa . h  + wb . g   (10 pk_fma + 1 hsum)
__device__ __forceinline__ float dot2W(const W5& wa, v4f ha, v4f hb, v2f hc,
                                       const W5& wb, v4f ga, v4f gb, v2f gc, float bias) {
    v2f acc = (v2f){bias, 0.0f};
    acc = pkfma(wa.p[0], lo2(ha), acc);
    acc = pkfma(wa.p[1], hi2(ha), acc);
    acc = pkfma(wa.p[2], lo2(hb), acc);
    acc = pkfma(wa.p[3], hi2(hb), acc);
    acc = pkfma(wa.p[4], hc, acc);
    acc = pkfma(wb.p[0], lo2(ga), acc);
    acc = pkfma(wb.p[1], hi2(ga), acc);
    acc = pkfma(wb.p[2], lo2(gb), acc);
    acc = pkfma(wb.p[3], hi2(gb), acc);
    acc = pkfma(wb.p[4], gc, acc);
    return acc.x + acc.y;
}

__attribute__((amdgpu_waves_per_eu(2, 2)))
__global__ __launch_bounds__(256) void gru_fused(
    const float* __restrict__ X,
    const float* __restrict__ Wih0, const float* __restrict__ Whh0,
    const float* __restrict__ bih0, const float* __restrict__ bhh0,
    const float* __restrict__ Wih1, const float* __restrict__ Whh1,
    const float* __restrict__ bih1, const float* __restrict__ bhh1,
    const float* __restrict__ Wfc,  const float* __restrict__ bfc,
    float* __restrict__ out)
{
    // Broadcast buffer (R10 layout, read-conflict-free; writes <=2-way = ~1 cyc).
    __shared__ __align__(16) float hls[4][2][5][12];

    const int tid  = threadIdx.x;
    const int lane = tid & 63;
    const int wave = tid >> 6;
    const int g    = lane / 10;      // 0..3 real, 4..6 idle
    const int j    = lane - g * 10;  // 0..9
    const int gg   = (g < 4) ? g : 4;  // idle lanes use dump row 4

    const bool active = (g < ROWS_PER_WAVE);
    int b = blockIdx.x * ROWS_PER_BLOCK + wave * ROWS_PER_WAVE + (active ? g : 0);
    const bool store_ok = active && (b < NB);
    if (b >= NB) b = NB - 1;

    const int r0 = j, r1 = j + 10, r2 = j + 20;
    const float Sz = -LOG2E;         // r,z rows: sigmoid in log2 domain
    const float Sn = 2.0f * LOG2E;   // n rows: tanh in log2 domain

    // ---- per-lane weights, pre-scaled into the log2 domain (NON-const: pinned) ----
    v2f wxr = (v2f){Wih0[r0 * 2] * Sz, Wih0[r0 * 2 + 1] * Sz};
    v2f wxz = (v2f){Wih0[r1 * 2] * Sz, Wih0[r1 * 2 + 1] * Sz};
    v2f wxn = (v2f){Wih0[r2 * 2] * Sn, Wih0[r2 * 2 + 1] * Sn};

    W5 whr0 = loadrow_scaled(Whh0 + r0 * NH, Sz);
    W5 whz0 = loadrow_scaled(Whh0 + r1 * NH, Sz);
    W5 whn0 = loadrow_scaled(Whh0 + r2 * NH, Sn);
    W5 wir1 = loadrow_scaled(Wih1 + r0 * NH, Sz);
    W5 wiz1 = loadrow_scaled(Wih1 + r1 * NH, Sz);
    W5 win1 = loadrow_scaled(Wih1 + r2 * NH, Sn);
    W5 whr1 = loadrow_scaled(Whh1 + r0 * NH, Sz);
    W5 whz1 = loadrow_scaled(Whh1 + r1 * NH, Sz);
    W5 whn1 = loadrow_scaled(Whh1 + r2 * NH, Sn);

    float br0  = (bih0[r0] + bhh0[r0]) * Sz;
    float bz0  = (bih0[r1] + bhh0[r1]) * Sz;
    float bxn0 = bih0[r2] * Sn;
    float bhn0 = bhh0[r2] * Sn;
    float br1  = (bih1[r0] + bhh1[r0]) * Sz;
    float bz1  = (bih1[r1] + bhh1[r1]) * Sz;
    float bxn1 = bih1[r2] * Sn;
    float bhn1 = bhh1[r2] * Sn;

    float* const L0 = &hls[wave][0][gg][0];
    float* const L1 = &hls[wave][1][gg][0];

    // replicated h state (zero initial)
    v4f h0a = (v4f){0,0,0,0}, h0b = (v4f){0,0,0,0}; v2f h0c = (v2f){0,0};
    v4f h1a = (v4f){0,0,0,0}, h1b = (v4f){0,0,0,0}; v2f h1c = (v2f){0,0};
    float my0 = 0.0f, my1 = 0.0f;

    const float2* xp = reinterpret_cast<const float2*>(X) + (size_t)b * NT;
    float2 xc = xp[0];
    float2 xn2;

// In-loop residency pins: every weight value is a tied "+v" operand of an
// opaque volatile asm executed each iteration. Post-asm values cannot be
// rematerialized from their defining loads, and spill/reload around the asm
// costs MORE than residency -> allocator's cheapest choice is keeping all
// ~145 floats in VGPRs (2 waves/SIMD budget = 256, matches our launch).
#define PINS()                                                                  \
    asm volatile("" : "+v"(whr0.p[0]), "+v"(whr0.p[1]), "+v"(whr0.p[2]),        \
                      "+v"(whr0.p[3]), "+v"(whr0.p[4]), "+v"(whz0.p[0]),        \
                      "+v"(whz0.p[1]), "+v"(whz0.p[2]), "+v"(whz0.p[3]),        \
                      "+v"(whz0.p[4]), "+v"(whn0.p[0]), "+v"(whn0.p[1]),        \
                      "+v"(whn0.p[2]), "+v"(whn0.p[3]), "+v"(whn0.p[4]));       \
    asm volatile("" : "+v"(wir1.p[0]), "+v"(wir1.p[1]), "+v"(wir1.p[2]),        \
                      "+v"(wir1.p[3]), "+v"(wir1.p[4]), "+v"(wiz1.p[0]),        \
                      "+v"(wiz1.p[1]), "+v"(wiz1.p[2]), "+v"(wiz1.p[3]),        \
                      "+v"(wiz1.p[4]), "+v"(win1.p[0]), "+v"(win1.p[1]),        \
                      "+v"(win1.p[2]), "+v"(win1.p[3]), "+v"(win1.p[4]));       \
    asm volatile("" : "+v"(whr1.p[0]), "+v"(whr1.p[1]), "+v"(whr1.p[2]),        \
                      "+v"(whr1.p[3]), "+v"(whr1.p[4]), "+v"(whz1.p[0]),        \
                      "+v"(whz1.p[1]), "+v"(whz1.p[2]), "+v"(whz1.p[3]),        \
                      "+v"(whz1.p[4]), "+v"(whn1.p[0]), "+v"(whn1.p[1]),        \
                      "+v"(whn1.p[2]), "+v"(whn1.p[3]), "+v"(whn1.p[4]));       \
    asm volatile("" : "+v"(wxr), "+v"(wxz), "+v"(wxn), "+v"(br0), "+v"(bz0),    \
                      "+v"(bxn0), "+v"(bhn0), "+v"(br1), "+v"(bz1),             \
                      "+v"(bxn1), "+v"(bhn1))

#define STEP(DO_PREFETCH, T)                                                    \
    do {                                                                        \
        PINS();                                                                 \
        if (DO_PREFETCH) xn2 = xp[(T) + 1];                                     \
        const v2f xv = (v2f){xc.x, xc.y};                                       \
        /* ---------- layer 0: acc seeded by input-side pk_fma ---------- */    \
        v2f accr = pkfma(wxr, xv, (v2f){br0, 0.0f});                            \
        v2f accz = pkfma(wxz, xv, (v2f){bz0, 0.0f});                            \
        v2f accx = pkfma(wxn, xv, (v2f){bxn0, 0.0f});                           \
        accr = pkfma(whr0.p[0], lo2(h0a), accr);                                \
        accr = pkfma(whr0.p[1], hi2(h0a), accr);                                \
        accr = pkfma(whr0.p[2], lo2(h0b), accr);                                \
        accr = pkfma(whr0.p[3], hi2(h0b), accr);                                \
        accr = pkfma(whr0.p[4], h0c, accr);                                     \
        accz = pkfma(whz0.p[0], lo2(h0a), accz);                                \
        accz = pkfma(whz0.p[1], hi2(h0a), accz);                                \
        accz = pkfma(whz0.p[2], lo2(h0b), accz);                                \
        accz = pkfma(whz0.p[3], hi2(h0b), accz);                                \
        accz = pkfma(whz0.p[4], h0c, accz);                                     \
        const float ph = dotW(whn0, h0a, h0b, h0c, bhn0);                       \
        const float pr = accr.x + accr.y;                                       \
        const float pz = accz.x + accz.y;                                       \
        const float px = accx.x + accx.y;                                       \
        const float r = sigm2q(pr);                                             \
        const float z = sigm2q(pz);                                             \
        const float n = tanh2u(fmaf(r, ph, px));                                \
        my0 = fmaf(z, my0 - n, n);                                              \
        L0[j] = my0;                                                            \
        h0a = *reinterpret_cast<const v4f*>(L0);                                \
        h0b = *reinterpret_cast<const v4f*>(L0 + 4);                            \
        h0c = *reinterpret_cast<const v2f*>(L0 + 8);                            \
        /* ---------- layer 1: fused 20-element dots for r,z ---------- */      \
        const float qr = dot2W(wir1, h0a, h0b, h0c, whr1, h1a, h1b, h1c, br1);  \
        const float qz = dot2W(wiz1, h0a, h0b, h0c, whz1, h1a, h1b, h1c, bz1);  \
        const float qx = dotW(win1, h0a, h0b, h0c, bxn1);                       \
        const float qh = dotW(whn1, h1a, h1b, h1c, bhn1);                       \
        const float r1v = sigm2q(qr);                                           \
        const float z1v = sigm2q(qz);                                           \
        const float n1v = tanh2u(fmaf(r1v, qh, qx));                            \
        my1 = fmaf(z1v, my1 - n1v, n1v);                                        \
        L1[j] = my1;                                                            \
        h1a = *reinterpret_cast<const v4f*>(L1);                                \
        h1b = *reinterpret_cast<const v4f*>(L1 + 4);                            \
        h1c = *reinterpret_cast<const v2f*>(L1 + 8);                            \
        if (DO_PREFETCH) xc = xn2;                                              \
    } while (0)

    for (int t = 0; t < NT - 1; ++t) {
        STEP(true, t);
    }
    STEP(false, NT - 1);   // peeled: no prefetch, no bounds select anywhere
#undef STEP
#undef PINS

    // ---- FC head ----
    if (store_ok && j < 2) {
        const W5 wf = loadrow_scaled(Wfc + j * NH, 1.0f);
        out[(size_t)b * 2 + j] = dotW(wf, h1a, h1b, h1c, bfc[j]);
    }
}

extern "C" void kernel_launch(void* const* d_in, const int* in_sizes, int n_in,
                              void* d_out, int out_size, void* d_ws, size_t ws_size,
                              hipStream_t stream) {
    const float* X    = (const float*)d_in[0];
    const float* Wih0 = (const float*)d_in[1];
    const float* Whh0 = (const float*)d_in[2];
    const float* bih0 = (const float*)d_in[3];
    const float* bhh0 = (const float*)d_in[4];
    const float* Wih1 = (const float*)d_in[5];
    const float* Whh1 = (const float*)d_in[6];
    const float* bih1 = (const float*)d_in[7];
    const float* bhh1 = (const float*)d_in[8];
    const float* Wfc  = (const float*)d_in[9];
    const float* bfc  = (const float*)d_in[10];
    float* out = (float*)d_out;

    const int grid = NB / ROWS_PER_BLOCK;  // 512 blocks -> 2048 waves = 2/SIMD
    gru_fused<<<grid, 256, 0, stream>>>(X, Wih0, Whh0, bih0, bhh0,
                                        Wih1, Whh1, bih1, bhh1, Wfc, bfc, out);
}

// Round 18
// 427.149 us; speedup vs baseline: 1.0951x; 1.0951x over previous
//
#include <hip/hip_runtime.h>

#define NB 8192
#define NT 1024
#define NH 10
#define ROWS_PER_WAVE 4     // 10 lanes/row, lanes 40..63 idle
#define ROWS_PER_BLOCK 16   // 4 waves/block

typedef float v2f __attribute__((ext_vector_type(2)));
typedef float v4f __attribute__((ext_vector_type(4)));

#define LOG2E 1.44269504088896340736f

__device__ __forceinline__ float rcpf(float x) { return __builtin_amdgcn_rcpf(x); }
__device__ __forceinline__ float exp2i(float x) {   // single v_exp_f32, no libm guards
    float r;
    asm("v_exp_f32 %0, %1" : "=v"(r) : "v"(x));
    return r;
}
// u accumulated with 2*log2e pre-scaled weights: tanh = 1 - 2/(2^u + 1)
__device__ __forceinline__ float tanh2u(float u) { return fmaf(-2.0f, rcpf(exp2i(u) + 1.0f), 1.0f); }
// paired sigmoid, ONE rcp (R6-validated): sa=1/(1+2^qa), sb=1/(1+2^qb)
// |q| <~ 30 -> product <~ 2^31*2^31? no: da,db in [1, 2^30]; da*db < 2^60 finite. Safe.
__device__ __forceinline__ void sigm2q2(float qa, float qb, float& sa, float& sb) {
    const float da = 1.0f + exp2i(qa);
    const float db = 1.0f + exp2i(qb);
    const float R = rcpf(da * db);
    sa = db * R;
    sb = da * R;
}

__device__ __forceinline__ v2f lo2(v4f a) { return __builtin_shufflevector(a, a, 0, 1); }
__device__ __forceinline__ v2f hi2(v4f a) { return __builtin_shufflevector(a, a, 2, 3); }
__device__ __forceinline__ v2f pkfma(v2f a, v2f b, v2f c) {  // -> v_pk_fma_f32 (no asm)
    return __builtin_elementwise_fma(a, b, c);
}

// Row of 10 weights as 5 v2f pairs (pk_fma operands).
struct W5 { v2f p[5]; };
__device__ __forceinline__ W5 loadrow_scaled(const float* __restrict__ q, float s) {
    W5 w;
#pragma unroll
    for (int k = 0; k < 5; ++k) w.p[k] = (v2f){q[2 * k] * s, q[2 * k + 1] * s};
    return w;
}
// seed + w . h   (5 pk_fma into a v2f acc; caller hsums)
__device__ __forceinline__ v2f dotWacc(const W5& w, v4f ha, v4f hb, v2f hc, v2f acc) {
    acc = pkfma(w.p[0], lo2(ha), acc);
    acc = pkfma(w.p[1], hi2(ha), acc);
    acc = pkfma(w.p[2], lo2(hb), acc);
    acc = pkfma(w.p[3], hi2(hb), acc);
    acc = pkfma(w.p[4], hc, acc);
    return acc;
}
__device__ __forceinline__ float hsum(v2f a) { return a.x + a.y; }

__global__ __launch_bounds__(256) void gru_fused(
    const float* __restrict__ X,
    const float* __restrict__ Wih0, const float* __restrict__ Whh0,
    const float* __restrict__ bih0, const float* __restrict__ bhh0,
    const float* __restrict__ Wih1, const float* __restrict__ Whh1,
    const float* __restrict__ bih1, const float* __restrict__ bhh1,
    const float* __restrict__ Wfc,  const float* __restrict__ bfc,
    float* __restrict__ out)
{
    // Broadcast buffer (R10 layout, read-conflict-free; writes <=2-way = ~1 cyc).
    __shared__ __align__(16) float hls[4][2][5][12];

    const int tid  = threadIdx.x;
    const int lane = tid & 63;
    const int wave = tid >> 6;
    const int g    = lane / 10;      // 0..3 real, 4..6 idle
    const int j    = lane - g * 10;  // 0..9
    const int gg   = (g < 4) ? g : 4;  // idle lanes use dump row 4

    const bool active = (g < ROWS_PER_WAVE);
    int b = blockIdx.x * ROWS_PER_BLOCK + wave * ROWS_PER_WAVE + (active ? g : 0);
    const bool store_ok = active && (b < NB);
    if (b >= NB) b = NB - 1;

    const int r0 = j, r1 = j + 10, r2 = j + 20;
    const float Sz = -LOG2E;         // r,z rows: sigmoid in log2 domain
    const float Sn = 2.0f * LOG2E;   // n rows: tanh in log2 domain

    // ---- per-lane weights, pre-scaled into the log2 domain ----
    const v2f wxr = (v2f){Wih0[r0 * 2] * Sz, Wih0[r0 * 2 + 1] * Sz};
    const v2f wxz = (v2f){Wih0[r1 * 2] * Sz, Wih0[r1 * 2 + 1] * Sz};
    const v2f wxn = (v2f){Wih0[r2 * 2] * Sn, Wih0[r2 * 2 + 1] * Sn};

    const W5 whr0 = loadrow_scaled(Whh0 + r0 * NH, Sz);
    const W5 whz0 = loadrow_scaled(Whh0 + r1 * NH, Sz);
    const W5 whn0 = loadrow_scaled(Whh0 + r2 * NH, Sn);
    const W5 wir1 = loadrow_scaled(Wih1 + r0 * NH, Sz);
    const W5 wiz1 = loadrow_scaled(Wih1 + r1 * NH, Sz);
    const W5 win1 = loadrow_scaled(Wih1 + r2 * NH, Sn);
    const W5 whr1 = loadrow_scaled(Whh1 + r0 * NH, Sz);
    const W5 whz1 = loadrow_scaled(Whh1 + r1 * NH, Sz);
    const W5 whn1 = loadrow_scaled(Whh1 + r2 * NH, Sn);

    const float br0  = (bih0[r0] + bhh0[r0]) * Sz;
    const float bz0  = (bih0[r1] + bhh0[r1]) * Sz;
    const float bxn0 = bih0[r2] * Sn;
    const float bhn0 = bhh0[r2] * Sn;
    const float br1  = (bih1[r0] + bhh1[r0]) * Sz;
    const float bz1  = (bih1[r1] + bhh1[r1]) * Sz;
    const float bxn1 = bih1[r2] * Sn;
    const float bhn1 = bhh1[r2] * Sn;

    float* const L0 = &hls[wave][0][gg][0];
    float* const L1 = &hls[wave][1][gg][0];

    // replicated h state (zero initial)
    v4f h0a = (v4f){0,0,0,0}, h0b = (v4f){0,0,0,0}; v2f h0c = (v2f){0,0};
    v4f h1a = (v4f){0,0,0,0}, h1b = (v4f){0,0,0,0}; v2f h1c = (v2f){0,0};
    float my0 = 0.0f, my1 = 0.0f;

    const float2* xp = reinterpret_cast<const float2*>(X) + (size_t)b * NT;
    float2 xc = xp[0];
    float2 xn2;

#define STEP(DO_PREFETCH, T)                                                    \
    do {                                                                        \
        if (DO_PREFETCH) xn2 = xp[(T) + 1];                                     \
        const v2f xv = (v2f){xc.x, xc.y};                                       \
        /* ---------- layer 0 ---------- */                                     \
        v2f accr = pkfma(wxr, xv, (v2f){br0, 0.0f});                            \
        v2f accz = pkfma(wxz, xv, (v2f){bz0, 0.0f});                            \
        v2f accx = pkfma(wxn, xv, (v2f){bxn0, 0.0f});                           \
        accr = dotWacc(whr0, h0a, h0b, h0c, accr);                              \
        accz = dotWacc(whz0, h0a, h0b, h0c, accz);                              \
        const v2f acch = dotWacc(whn0, h0a, h0b, h0c, (v2f){bhn0, 0.0f});       \
        float r, z;                                                             \
        sigm2q2(hsum(accr), hsum(accz), r, z);                                  \
        const float n = tanh2u(fmaf(r, hsum(acch), hsum(accx)));                \
        my0 = fmaf(z, my0 - n, n);                                              \
        /* L0 broadcast: write + issue reads, then fill the round-trip     */   \
        /* latency with h1-only chains (independent of the pending reads). */   \
        L0[j] = my0;                                                            \
        const v4f nh0a = *reinterpret_cast<const v4f*>(L0);                     \
        const v4f nh0b = *reinterpret_cast<const v4f*>(L0 + 4);                 \
        const v2f nh0c = *reinterpret_cast<const v2f*>(L0 + 8);                 \
        /* ---------- layer 1, h1-dependent part FIRST ---------- */            \
        v2f aqr = dotWacc(whr1, h1a, h1b, h1c, (v2f){br1, 0.0f});               \
        v2f aqz = dotWacc(whz1, h1a, h1b, h1c, (v2f){bz1, 0.0f});               \
        const v2f aqh = dotWacc(whn1, h1a, h1b, h1c, (v2f){bhn1, 0.0f});        \
        /* ---------- layer 1, h0-dependent part (after the wait) -------- */   \
        h0a = nh0a; h0b = nh0b; h0c = nh0c;                                     \
        aqr = dotWacc(wir1, h0a, h0b, h0c, aqr);                                \
        aqz = dotWacc(wiz1, h0a, h0b, h0c, aqz);                                \
        const v2f aqx = dotWacc(win1, h0a, h0b, h0c, (v2f){bxn1, 0.0f});        \
        float r1v, z1v;                                                         \
        sigm2q2(hsum(aqr), hsum(aqz), r1v, z1v);                                \
        const float n1v = tanh2u(fmaf(r1v, hsum(aqh), hsum(aqx)));              \
        my1 = fmaf(z1v, my1 - n1v, n1v);                                        \
        L1[j] = my1;                                                            \
        h1a = *reinterpret_cast<const v4f*>(L1);                                \
        h1b = *reinterpret_cast<const v4f*>(L1 + 4);                            \
        h1c = *reinterpret_cast<const v2f*>(L1 + 8);                            \
        if (DO_PREFETCH) xc = xn2;                                              \
    } while (0)

    for (int t = 0; t < NT - 1; ++t) {
        STEP(true, t);
    }
    STEP(false, NT - 1);   // peeled: no prefetch, no bounds select anywhere
#undef STEP

    // ---- FC head ----
    if (store_ok && j < 2) {
        const W5 wf = loadrow_scaled(Wfc + j * NH, 1.0f);
        out[(size_t)b * 2 + j] = hsum(dotWacc(wf, h1a, h1b, h1c, (v2f){bfc[j], 0.0f}));
    }
}

extern "C" void kernel_launch(void* const* d_in, const int* in_sizes, int n_in,
                              void* d_out, int out_size, void* d_ws, size_t ws_size,
                              hipStream_t stream) {
    const float* X    = (const float*)d_in[0];
    const float* Wih0 = (const float*)d_in[1];
    const float* Whh0 = (const float*)d_in[2];
    const float* bih0 = (const float*)d_in[3];
    const float* bhh0 = (const float*)d_in[4];
    const float* Wih1 = (const float*)d_in[5];
    const float* Whh1 = (const float*)d_in[6];
    const float* bih1 = (const float*)d_in[7];
    const float* bhh1 = (const float*)d_in[8];
    const float* Wfc  = (const float*)d_in[9];
    const float* bfc  = (const float*)d_in[10];
    float* out = (float*)d_out;

    const int grid = NB / ROWS_PER_BLOCK;  // 512 blocks -> 2048 waves = 2/SIMD
    gru_fused<<<grid, 256, 0, stream>>>(X, Wih0, Whh0, bih0, bhh0,
                                        Wih1, Whh1, bih1, bhh1, Wfc, bfc, out);
}

// Round 19
// 414.332 us; speedup vs baseline: 1.1290x; 1.0309x over previous
//
#include <hip/hip_runtime.h>

#define NB 8192
#define NT 1024
#define NH 10
#define ROWS_PER_WAVE 4     // 10 lanes/row, lanes 40..63 idle
#define ROWS_PER_BLOCK 16   // 4 waves/block

typedef float v2f __attribute__((ext_vector_type(2)));
typedef float v4f __attribute__((ext_vector_type(4)));

#define LOG2E 1.44269504088896340736f

__device__ __forceinline__ float rcpf(float x) { return __builtin_amdgcn_rcpf(x); }
__device__ __forceinline__ float exp2i(float x) {
#if __has_builtin(__builtin_amdgcn_exp2f)
    return __builtin_amdgcn_exp2f(x);   // scheduler-friendly v_exp_f32
#else
    float r;
    asm("v_exp_f32 %0, %1" : "=v"(r) : "v"(x));
    return r;
#endif
}
// u accumulated with 2*log2e pre-scaled weights: tanh = 1 - 2/(2^u + 1)
__device__ __forceinline__ float tanh2u(float u) { return fmaf(-2.0f, rcpf(exp2i(u) + 1.0f), 1.0f); }
// paired sigmoid, ONE rcp: sa=1/(1+2^qa), sb=1/(1+2^qb); da,db in [1,2^30] -> product finite
__device__ __forceinline__ void sigm2q2(float qa, float qb, float& sa, float& sb) {
    const float da = 1.0f + exp2i(qa);
    const float db = 1.0f + exp2i(qb);
    const float R = rcpf(da * db);
    sa = db * R;
    sb = da * R;
}

__device__ __forceinline__ v2f lo2(v4f a) { return __builtin_shufflevector(a, a, 0, 1); }
__device__ __forceinline__ v2f hi2(v4f a) { return __builtin_shufflevector(a, a, 2, 3); }
__device__ __forceinline__ v2f pkfma(v2f a, v2f b, v2f c) {  // -> v_pk_fma_f32
    return __builtin_elementwise_fma(a, b, c);
}

// Row of 10 weights as 5 v2f pairs (pk_fma operands).
struct W5 { v2f p[5]; };
__device__ __forceinline__ W5 loadrow_scaled(const float* __restrict__ q, float s) {
    W5 w;
#pragma unroll
    for (int k = 0; k < 5; ++k) w.p[k] = (v2f){q[2 * k] * s, q[2 * k + 1] * s};
    return w;
}
// acc += w . h   (5 pk_fma into a v2f acc; caller hsums)
__device__ __forceinline__ v2f dotWacc(const W5& w, v4f ha, v4f hb, v2f hc, v2f acc) {
    acc = pkfma(w.p[0], lo2(ha), acc);
    acc = pkfma(w.p[1], hi2(ha), acc);
    acc = pkfma(w.p[2], lo2(hb), acc);
    acc = pkfma(w.p[3], hi2(hb), acc);
    acc = pkfma(w.p[4], hc, acc);
    return acc;
}
__device__ __forceinline__ float hsum(v2f a) { return a.x + a.y; }

__global__ __launch_bounds__(256) void gru_fused(
    const float* __restrict__ X,
    const float* __restrict__ Wih0, const float* __restrict__ Whh0,
    const float* __restrict__ bih0, const float* __restrict__ bhh0,
    const float* __restrict__ Wih1, const float* __restrict__ Whh1,
    const float* __restrict__ bih1, const float* __restrict__ bhh1,
    const float* __restrict__ Wfc,  const float* __restrict__ bfc,
    float* __restrict__ out)
{
    // Broadcast buffer (R10 layout, read-conflict-free; writes <=2-way = ~1 cyc).
    __shared__ __align__(16) float hls[4][2][5][12];

    const int tid  = threadIdx.x;
    const int lane = tid & 63;
    const int wave = tid >> 6;
    const int g    = lane / 10;      // 0..3 real, 4..6 idle
    const int j    = lane - g * 10;  // 0..9
    const int gg   = (g < 4) ? g : 4;  // idle lanes use dump row 4

    const bool active = (g < ROWS_PER_WAVE);
    int b = blockIdx.x * ROWS_PER_BLOCK + wave * ROWS_PER_WAVE + (active ? g : 0);
    const bool store_ok = active && (b < NB);
    if (b >= NB) b = NB - 1;

    const int r0 = j, r1 = j + 10, r2 = j + 20;
    const float Sz = -LOG2E;         // r,z rows: sigmoid in log2 domain
    const float Sn = 2.0f * LOG2E;   // n rows: tanh in log2 domain

    // ---- per-lane weights, pre-scaled into the log2 domain ----
    const v2f wxr = (v2f){Wih0[r0 * 2] * Sz, Wih0[r0 * 2 + 1] * Sz};
    const v2f wxz = (v2f){Wih0[r1 * 2] * Sz, Wih0[r1 * 2 + 1] * Sz};
    const v2f wxn = (v2f){Wih0[r2 * 2] * Sn, Wih0[r2 * 2 + 1] * Sn};

    const W5 whr0 = loadrow_scaled(Whh0 + r0 * NH, Sz);
    const W5 whz0 = loadrow_scaled(Whh0 + r1 * NH, Sz);
    const W5 whn0 = loadrow_scaled(Whh0 + r2 * NH, Sn);
    const W5 wir1 = loadrow_scaled(Wih1 + r0 * NH, Sz);
    const W5 wiz1 = loadrow_scaled(Wih1 + r1 * NH, Sz);
    const W5 win1 = loadrow_scaled(Wih1 + r2 * NH, Sn);
    const W5 whr1 = loadrow_scaled(Whh1 + r0 * NH, Sz);
    const W5 whz1 = loadrow_scaled(Whh1 + r1 * NH, Sz);
    const W5 whn1 = loadrow_scaled(Whh1 + r2 * NH, Sn);

    // hoisted gate-bias seed vectors (loop-invariant)
    const v2f sr0 = (v2f){(bih0[r0] + bhh0[r0]) * Sz, 0.0f};
    const v2f sz0 = (v2f){(bih0[r1] + bhh0[r1]) * Sz, 0.0f};
    const v2f sx0 = (v2f){bih0[r2] * Sn, 0.0f};
    const v2f sh0 = (v2f){bhh0[r2] * Sn, 0.0f};
    const v2f sr1 = (v2f){(bih1[r0] + bhh1[r0]) * Sz, 0.0f};
    const v2f sz1 = (v2f){(bih1[r1] + bhh1[r1]) * Sz, 0.0f};
    const v2f sx1 = (v2f){bih1[r2] * Sn, 0.0f};
    const v2f sh1 = (v2f){bhh1[r2] * Sn, 0.0f};

    float* const L0 = &hls[wave][0][gg][0];
    float* const L1 = &hls[wave][1][gg][0];

    // h0 regs = h0(t-1); h1 regs = h1(t-2) (consumed from nh1 each iter)
    v4f h0a = (v4f){0,0,0,0}, h0b = (v4f){0,0,0,0}; v2f h0c = (v2f){0,0};
    v4f h1a, h1b; v2f h1c;
    v4f nh1a = (v4f){0,0,0,0}, nh1b = (v4f){0,0,0,0}; v2f nh1c = (v2f){0,0};
    float my0 = 0.0f, my1 = 0.0f;

    const float2* xp = reinterpret_cast<const float2*>(X) + (size_t)b * NT;
    float2 xc = xp[0];
    float2 xn2;

    v2f accr, accz, accx, acch, aqr, aqz, aqx, aqh;
    v4f nh0a, nh0b; v2f nh0c;
    float r0v, z0v, n0v, r1v, z1v, n1v;

    // L0 gate computation for x=xv, h0 = (h0a,h0b,h0c); writes + issues reads of h0(t)
#define L0_GATES(xv)                                                            \
    accr = pkfma(wxr, xv, sr0);                                                 \
    accz = pkfma(wxz, xv, sz0);                                                 \
    accx = pkfma(wxn, xv, sx0);                                                 \
    accr = dotWacc(whr0, h0a, h0b, h0c, accr);                                  \
    accz = dotWacc(whz0, h0a, h0b, h0c, accz);                                  \
    acch = dotWacc(whn0, h0a, h0b, h0c, sh0);                                   \
    sigm2q2(hsum(accr), hsum(accz), r0v, z0v);                                  \
    n0v = tanh2u(fmaf(r0v, hsum(acch), hsum(accx)));                            \
    my0 = fmaf(z0v, my0 - n0v, n0v);                                            \
    L0[j] = my0;                                                                \
    nh0a = *reinterpret_cast<const v4f*>(L0);                                   \
    nh0b = *reinterpret_cast<const v4f*>(L0 + 4);                               \
    nh0c = *reinterpret_cast<const v2f*>(L0 + 8)

    // L1 gates for step whose h0 is CURRENT regs and h1 = (h1a,h1b,h1c)
#define L1_GATES()                                                              \
    aqr = dotWacc(whr1, h1a, h1b, h1c, sr1);                                    \
    aqz = dotWacc(whz1, h1a, h1b, h1c, sz1);                                    \
    aqh = dotWacc(whn1, h1a, h1b, h1c, sh1);                                    \
    aqr = dotWacc(wir1, h0a, h0b, h0c, aqr);                                    \
    aqz = dotWacc(wiz1, h0a, h0b, h0c, aqz);                                    \
    aqx = dotWacc(win1, h0a, h0b, h0c, sx1);                                    \
    sigm2q2(hsum(aqr), hsum(aqz), r1v, z1v);                                    \
    n1v = tanh2u(fmaf(r1v, hsum(aqh), hsum(aqx)));                              \
    my1 = fmaf(z1v, my1 - n1v, n1v)

    // -------- prologue: L0 step t=0 (h0(-1)=0); one-time exposed round-trip --------
    {
        const v2f xv = (v2f){xc.x, xc.y};
        L0_GATES(xv);
        h0a = nh0a; h0b = nh0b; h0c = nh0c;   // h0(0)
        xc = xp[1];
    }

    // -------- pipelined main loop: iter t does L0(t) and L1(t-1) --------
    for (int t = 1; t < NT; ++t) {
        xn2 = xp[(t + 1 < NT) ? (t + 1) : (NT - 1)];
        const v2f xv = (v2f){xc.x, xc.y};
        // L0(t): uses h0(t-1) in regs; issues h0(t) reads
        L0_GATES(xv);
        // consume h1(t-2) (issued at bottom of previous iter -> long since complete)
        h1a = nh1a; h1b = nh1b; h1c = nh1c;
        // L1(t-1): uses h0(t-1) (still in regs) + h1(t-2); its ~150cyc stream
        // covers L0's LDS round-trip
        L1_GATES();
        // consume h0(t) (round-trip fully covered by L1 compute)
        h0a = nh0a; h0b = nh0b; h0c = nh0c;
        // write h1(t-1), issue reads; consumed next iteration (covered by L0(t+1))
        L1[j] = my1;
        nh1a = *reinterpret_cast<const v4f*>(L1);
        nh1b = *reinterpret_cast<const v4f*>(L1 + 4);
        nh1c = *reinterpret_cast<const v2f*>(L1 + 8);
        xc = xn2;
    }

    // -------- epilogue: L1 step t=NT-1 --------
    {
        h1a = nh1a; h1b = nh1b; h1c = nh1c;   // h1(NT-2)
        L1_GATES();                            // uses h0(NT-1) in regs
        L1[j] = my1;
        h1a = *reinterpret_cast<const v4f*>(L1);
        h1b = *reinterpret_cast<const v4f*>(L1 + 4);
        h1c = *reinterpret_cast<const v2f*>(L1 + 8);
    }
#undef L0_GATES
#undef L1_GATES

    // ---- FC head ----
    if (store_ok && j < 2) {
        const W5 wf = loadrow_scaled(Wfc + j * NH, 1.0f);
        out[(size_t)b * 2 + j] = hsum(dotWacc(wf, h1a, h1b, h1c, (v2f){bfc[j], 0.0f}));
    }
}

extern "C" void kernel_launch(void* const* d_in, const int* in_sizes, int n_in,
                              void* d_out, int out_size, void* d_ws, size_t ws_size,
                              hipStream_t stream) {
    const float* X    = (const float*)d_in[0];
    const float* Wih0 = (const float*)d_in[1];
    const float* Whh0 = (const float*)d_in[2];
    const float* bih0 = (const float*)d_in[3];
    const float* bhh0 = (const float*)d_in[4];
    const float* Wih1 = (const float*)d_in[5];
    const float* Whh1 = (const float*)d_in[6];
    const float* bih1 = (const float*)d_in[7];
    const float* bhh1 = (const float*)d_in[8];
    const float* Wfc  = (const float*)d_in[9];
    const float* bfc  = (const float*)d_in[10];
    float* out = (float*)d_out;

    const int grid = NB / ROWS_PER_BLOCK;  // 512 blocks -> 2048 waves = 2/SIMD
    gru_fused<<<grid, 256, 0, stream>>>(X, Wih0, Whh0, bih0, bhh0,
                                        Wih1, Whh1, bih1, bhh1, Wfc, bfc, out);
}